// Round 1
// baseline (9275.492 us; speedup 1.0000x reference)
//
#include <hip/hip_runtime.h>

#define TSTEPS 100
#define DIN    4
#define HDIM   64
#define BC     64          // batch elements per block
#define UPW    16          // hidden units per wave (HDIM / 4 waves)
#define NBLK   (16384/BC)  // 256 blocks

__device__ __forceinline__ float fsig(float x) {
    return 1.0f / (1.0f + __expf(-x));
}
__device__ __forceinline__ float ftanh(float x) {
    // tanh(x) = 1 - 2/(exp(2x)+1); saturates correctly at +/-1
    float e = __expf(2.0f * x);
    return 1.0f - 2.0f / (e + 1.0f);
}

__global__ __launch_bounds__(256, 1) void lstm2_ln_fc(
    const float* __restrict__ x,
    const float* __restrict__ Wih0, const float* __restrict__ Whh0,
    const float* __restrict__ bih0, const float* __restrict__ bhh0,
    const float* __restrict__ Wih1, const float* __restrict__ Whh1,
    const float* __restrict__ bih1, const float* __restrict__ bhh1,
    const float* __restrict__ gam,  const float* __restrict__ bet,
    const float* __restrict__ Wfc,  const float* __restrict__ bfc,
    float* __restrict__ out)
{
    // [unit][batch] layout: every LDS access is stride-1 across lanes -> conflict-free
    __shared__ float H0[2][HDIM][BC];
    __shared__ float H1[2][HDIM][BC];
    __shared__ float C0[HDIM][BC];
    __shared__ float C1[HDIM][BC];

    const int lane = threadIdx.x & 63;
    const int wave = threadIdx.x >> 6;
    const int j0   = wave * UPW;
    const int b    = blockIdx.x * BC + lane;

    #pragma unroll
    for (int u = 0; u < UPW; ++u) {
        H0[0][j0 + u][lane] = 0.0f;
        H1[0][j0 + u][lane] = 0.0f;
        C0[j0 + u][lane]    = 0.0f;
        C1[j0 + u][lane]    = 0.0f;
    }
    __syncthreads();

    const float4* __restrict__ xb =
        reinterpret_cast<const float4*>(x + (size_t)b * (TSTEPS * DIN));

    float h0r[HDIM], h1r[HDIM];

    for (int t = 0; t < TSTEPS; ++t) {
        const int cur = t & 1, nxt = cur ^ 1;
        const float4 xv = xb[t];

        // ---------------- layer 0 ----------------
        #pragma unroll
        for (int k = 0; k < HDIM; ++k) h0r[k] = H0[cur][k][lane];

        #pragma unroll 2
        for (int u = 0; u < UPW; ++u) {
            const int r = j0 + u;
            float a0 = bih0[r]       + bhh0[r];
            float a1 = bih0[r + 64]  + bhh0[r + 64];
            float a2 = bih0[r + 128] + bhh0[r + 128];
            float a3 = bih0[r + 192] + bhh0[r + 192];
            const float* wxi = Wih0 + (size_t)r * DIN;
            const float* wxf = Wih0 + (size_t)(r + 64) * DIN;
            const float* wxg = Wih0 + (size_t)(r + 128) * DIN;
            const float* wxo = Wih0 + (size_t)(r + 192) * DIN;
            a0 = fmaf(wxi[0], xv.x, fmaf(wxi[1], xv.y, fmaf(wxi[2], xv.z, fmaf(wxi[3], xv.w, a0))));
            a1 = fmaf(wxf[0], xv.x, fmaf(wxf[1], xv.y, fmaf(wxf[2], xv.z, fmaf(wxf[3], xv.w, a1))));
            a2 = fmaf(wxg[0], xv.x, fmaf(wxg[1], xv.y, fmaf(wxg[2], xv.z, fmaf(wxg[3], xv.w, a2))));
            a3 = fmaf(wxo[0], xv.x, fmaf(wxo[1], xv.y, fmaf(wxo[2], xv.z, fmaf(wxo[3], xv.w, a3))));
            const float* wi = Whh0 + (size_t)r * HDIM;
            const float* wf = Whh0 + (size_t)(r + 64) * HDIM;
            const float* wg = Whh0 + (size_t)(r + 128) * HDIM;
            const float* wo = Whh0 + (size_t)(r + 192) * HDIM;
            #pragma unroll
            for (int k = 0; k < HDIM; ++k) {
                const float h = h0r[k];
                a0 = fmaf(wi[k], h, a0);
                a1 = fmaf(wf[k], h, a1);
                a2 = fmaf(wg[k], h, a2);
                a3 = fmaf(wo[k], h, a3);
            }
            const float ig = fsig(a0), fg = fsig(a1);
            const float gg = ftanh(a2), og = fsig(a3);
            const float c  = fg * C0[r][lane] + ig * gg;
            C0[r][lane] = c;
            H0[nxt][r][lane] = og * ftanh(c);
        }
        __syncthreads();   // new h0 visible to all waves

        // ---------------- layer 1 ----------------
        #pragma unroll
        for (int k = 0; k < HDIM; ++k) h0r[k] = H0[nxt][k][lane];
        #pragma unroll
        for (int k = 0; k < HDIM; ++k) h1r[k] = H1[cur][k][lane];

        #pragma unroll 2
        for (int u = 0; u < UPW; ++u) {
            const int r = j0 + u;
            float a0 = bih1[r]       + bhh1[r];
            float a1 = bih1[r + 64]  + bhh1[r + 64];
            float a2 = bih1[r + 128] + bhh1[r + 128];
            float a3 = bih1[r + 192] + bhh1[r + 192];
            const float* vi = Wih1 + (size_t)r * HDIM;
            const float* vf = Wih1 + (size_t)(r + 64) * HDIM;
            const float* vg = Wih1 + (size_t)(r + 128) * HDIM;
            const float* vo = Wih1 + (size_t)(r + 192) * HDIM;
            #pragma unroll
            for (int k = 0; k < HDIM; ++k) {
                const float h = h0r[k];
                a0 = fmaf(vi[k], h, a0);
                a1 = fmaf(vf[k], h, a1);
                a2 = fmaf(vg[k], h, a2);
                a3 = fmaf(vo[k], h, a3);
            }
            const float* wi = Whh1 + (size_t)r * HDIM;
            const float* wf = Whh1 + (size_t)(r + 64) * HDIM;
            const float* wg = Whh1 + (size_t)(r + 128) * HDIM;
            const float* wo = Whh1 + (size_t)(r + 192) * HDIM;
            #pragma unroll
            for (int k = 0; k < HDIM; ++k) {
                const float h = h1r[k];
                a0 = fmaf(wi[k], h, a0);
                a1 = fmaf(wf[k], h, a1);
                a2 = fmaf(wg[k], h, a2);
                a3 = fmaf(wo[k], h, a3);
            }
            const float ig = fsig(a0), fg = fsig(a1);
            const float gg = ftanh(a2), og = fsig(a3);
            const float c  = fg * C1[r][lane] + ig * gg;
            C1[r][lane] = c;
            H1[nxt][r][lane] = og * ftanh(c);
        }
        __syncthreads();   // new h1 visible; also protects next step's buffer reuse
    }

    // ---------------- LayerNorm + FC on last h1 ----------------
    if (wave == 0) {
        const int fin = TSTEPS & 1;   // buffer holding h1[T-1]
        float mu = 0.0f;
        #pragma unroll
        for (int k = 0; k < HDIM; ++k) { h1r[k] = H1[fin][k][lane]; mu += h1r[k]; }
        mu *= (1.0f / HDIM);
        float var = 0.0f;
        #pragma unroll
        for (int k = 0; k < HDIM; ++k) { const float d = h1r[k] - mu; var = fmaf(d, d, var); }
        var *= (1.0f / HDIM);
        const float rs = rsqrtf(var + 1e-5f);
        float o0 = bfc[0], o1 = bfc[1];
        #pragma unroll
        for (int k = 0; k < HDIM; ++k) {
            const float nk = (h1r[k] - mu) * rs * gam[k] + bet[k];
            o0 = fmaf(nk, Wfc[k],        o0);
            o1 = fmaf(nk, Wfc[HDIM + k], o1);
        }
        out[(size_t)b * 2 + 0] = o0;
        out[(size_t)b * 2 + 1] = o1;
    }
}

extern "C" void kernel_launch(void* const* d_in, const int* in_sizes, int n_in,
                              void* d_out, int out_size, void* d_ws, size_t ws_size,
                              hipStream_t stream) {
    (void)in_sizes; (void)n_in; (void)out_size; (void)d_ws; (void)ws_size;
    const float* x    = (const float*)d_in[0];
    const float* Wih0 = (const float*)d_in[1];
    const float* Whh0 = (const float*)d_in[2];
    const float* bih0 = (const float*)d_in[3];
    const float* bhh0 = (const float*)d_in[4];
    const float* Wih1 = (const float*)d_in[5];
    const float* Whh1 = (const float*)d_in[6];
    const float* bih1 = (const float*)d_in[7];
    const float* bhh1 = (const float*)d_in[8];
    const float* gam  = (const float*)d_in[9];
    const float* bet  = (const float*)d_in[10];
    const float* Wfc  = (const float*)d_in[11];
    const float* bfc  = (const float*)d_in[12];
    float* out = (float*)d_out;

    hipLaunchKernelGGL(lstm2_ln_fc, dim3(NBLK), dim3(256), 0, stream,
                       x, Wih0, Whh0, bih0, bhh0, Wih1, Whh1, bih1, bhh1,
                       gam, bet, Wfc, bfc, out);
}

// Round 2
// 7343.829 us; speedup vs baseline: 1.2630x; 1.2630x over previous
//
#include <hip/hip_runtime.h>

#define TSTEPS 100
#define DIN    4
#define HDIM   64
#define BC     64          // batch elements per block (lane = batch)
#define NW     8           // waves per block
#define UPW    (HDIM/NW)   // hidden units per wave = 8
#define NBLK   (16384/BC)  // 256 blocks

__device__ __forceinline__ float fsig(float x) {
    return 1.0f / (1.0f + __expf(-x));
}
__device__ __forceinline__ float ftanh(float x) {
    float e = __expf(2.0f * x);
    return 1.0f - 2.0f / (e + 1.0f);
}

__global__ __launch_bounds__(NW*64, 1) void lstm2_ln_fc(
    const float* __restrict__ x,
    const float* __restrict__ Wih0, const float* __restrict__ Whh0,
    const float* __restrict__ bih0, const float* __restrict__ bhh0,
    const float* __restrict__ Wih1, const float* __restrict__ Whh1,
    const float* __restrict__ bih1, const float* __restrict__ bhh1,
    const float* __restrict__ gam,  const float* __restrict__ bet,
    const float* __restrict__ Wfc,  const float* __restrict__ bfc,
    float* __restrict__ out)
{
    // [unit][batch]: stride-1 across lanes -> conflict-free LDS
    __shared__ float H0[2][HDIM][BC];
    __shared__ float H1[2][HDIM][BC];

    const int lane = threadIdx.x & 63;
    const int wave = threadIdx.x >> 6;
    // Provably wave-uniform unit base -> compiler emits s_load for all
    // weight/bias accesses (weights live in SGPRs, fma uses SGPR operand).
    const int j0 = __builtin_amdgcn_readfirstlane(wave) * UPW;
    const int b  = blockIdx.x * BC + lane;

    if (wave < 4) {
        #pragma unroll
        for (int u = 0; u < UPW * 2; ++u) {
            H0[0][(wave * 2 * UPW) + u][lane] = 0.0f;
            H1[0][(wave * 2 * UPW) + u][lane] = 0.0f;
        }
    }
    __syncthreads();

    const float4* __restrict__ xb =
        reinterpret_cast<const float4*>(x + (size_t)b * (TSTEPS * DIN));

    float c0[UPW], c1[UPW];
    #pragma unroll
    for (int u = 0; u < UPW; ++u) { c0[u] = 0.0f; c1[u] = 0.0f; }

    float h0r[HDIM], h1r[HDIM];

    for (int t = 0; t < TSTEPS; ++t) {
        const int cur = t & 1, nxt = cur ^ 1;
        const float4 xv = xb[t];

        // ---------------- layer 0 ----------------
        #pragma unroll
        for (int k = 0; k < HDIM; ++k) h0r[k] = H0[cur][k][lane];

        #pragma unroll
        for (int u = 0; u < UPW; ++u) {
            const int r = j0 + u;                 // wave-uniform
            float a0 = bih0[r]       + bhh0[r];
            float a1 = bih0[r + 64]  + bhh0[r + 64];
            float a2 = bih0[r + 128] + bhh0[r + 128];
            float a3 = bih0[r + 192] + bhh0[r + 192];
            const float* wxi = Wih0 + (size_t)r * DIN;
            const float* wxf = Wih0 + (size_t)(r + 64) * DIN;
            const float* wxg = Wih0 + (size_t)(r + 128) * DIN;
            const float* wxo = Wih0 + (size_t)(r + 192) * DIN;
            a0 = fmaf(wxi[0], xv.x, fmaf(wxi[1], xv.y, fmaf(wxi[2], xv.z, fmaf(wxi[3], xv.w, a0))));
            a1 = fmaf(wxf[0], xv.x, fmaf(wxf[1], xv.y, fmaf(wxf[2], xv.z, fmaf(wxf[3], xv.w, a1))));
            a2 = fmaf(wxg[0], xv.x, fmaf(wxg[1], xv.y, fmaf(wxg[2], xv.z, fmaf(wxg[3], xv.w, a2))));
            a3 = fmaf(wxo[0], xv.x, fmaf(wxo[1], xv.y, fmaf(wxo[2], xv.z, fmaf(wxo[3], xv.w, a3))));
            const float* wi = Whh0 + (size_t)r * HDIM;
            const float* wf = Whh0 + (size_t)(r + 64) * HDIM;
            const float* wg = Whh0 + (size_t)(r + 128) * HDIM;
            const float* wo = Whh0 + (size_t)(r + 192) * HDIM;
            #pragma unroll
            for (int k = 0; k < HDIM; ++k) {
                const float h = h0r[k];
                a0 = fmaf(wi[k], h, a0);
                a1 = fmaf(wf[k], h, a1);
                a2 = fmaf(wg[k], h, a2);
                a3 = fmaf(wo[k], h, a3);
            }
            const float ig = fsig(a0), fg = fsig(a1);
            const float gg = ftanh(a2), og = fsig(a3);
            const float c  = fg * c0[u] + ig * gg;
            c0[u] = c;
            H0[nxt][r][lane] = og * ftanh(c);
        }
        __syncthreads();   // new h0 visible to all waves

        // ---------------- layer 1 ----------------
        #pragma unroll
        for (int k = 0; k < HDIM; ++k) h0r[k] = H0[nxt][k][lane];
        #pragma unroll
        for (int k = 0; k < HDIM; ++k) h1r[k] = H1[cur][k][lane];

        #pragma unroll
        for (int u = 0; u < UPW; ++u) {
            const int r = j0 + u;                 // wave-uniform
            float a0 = bih1[r]       + bhh1[r];
            float a1 = bih1[r + 64]  + bhh1[r + 64];
            float a2 = bih1[r + 128] + bhh1[r + 128];
            float a3 = bih1[r + 192] + bhh1[r + 192];
            const float* vi = Wih1 + (size_t)r * HDIM;
            const float* vf = Wih1 + (size_t)(r + 64) * HDIM;
            const float* vg = Wih1 + (size_t)(r + 128) * HDIM;
            const float* vo = Wih1 + (size_t)(r + 192) * HDIM;
            #pragma unroll
            for (int k = 0; k < HDIM; ++k) {
                const float h = h0r[k];
                a0 = fmaf(vi[k], h, a0);
                a1 = fmaf(vf[k], h, a1);
                a2 = fmaf(vg[k], h, a2);
                a3 = fmaf(vo[k], h, a3);
            }
            const float* wi = Whh1 + (size_t)r * HDIM;
            const float* wf = Whh1 + (size_t)(r + 64) * HDIM;
            const float* wg = Whh1 + (size_t)(r + 128) * HDIM;
            const float* wo = Whh1 + (size_t)(r + 192) * HDIM;
            #pragma unroll
            for (int k = 0; k < HDIM; ++k) {
                const float h = h1r[k];
                a0 = fmaf(wi[k], h, a0);
                a1 = fmaf(wf[k], h, a1);
                a2 = fmaf(wg[k], h, a2);
                a3 = fmaf(wo[k], h, a3);
            }
            const float ig = fsig(a0), fg = fsig(a1);
            const float gg = ftanh(a2), og = fsig(a3);
            const float c  = fg * c1[u] + ig * gg;
            c1[u] = c;
            H1[nxt][r][lane] = og * ftanh(c);
        }
        __syncthreads();
    }

    // ---------------- LayerNorm + FC on last h1 ----------------
    if (wave == 0) {
        const int fin = TSTEPS & 1;   // buffer holding h1[T-1]
        float mu = 0.0f;
        #pragma unroll
        for (int k = 0; k < HDIM; ++k) { h1r[k] = H1[fin][k][lane]; mu += h1r[k]; }
        mu *= (1.0f / HDIM);
        float var = 0.0f;
        #pragma unroll
        for (int k = 0; k < HDIM; ++k) { const float d = h1r[k] - mu; var = fmaf(d, d, var); }
        var *= (1.0f / HDIM);
        const float rs = rsqrtf(var + 1e-5f);
        float o0 = bfc[0], o1 = bfc[1];
        #pragma unroll
        for (int k = 0; k < HDIM; ++k) {
            const float nk = (h1r[k] - mu) * rs * gam[k] + bet[k];
            o0 = fmaf(nk, Wfc[k],        o0);
            o1 = fmaf(nk, Wfc[HDIM + k], o1);
        }
        out[(size_t)b * 2 + 0] = o0;
        out[(size_t)b * 2 + 1] = o1;
    }
}

extern "C" void kernel_launch(void* const* d_in, const int* in_sizes, int n_in,
                              void* d_out, int out_size, void* d_ws, size_t ws_size,
                              hipStream_t stream) {
    (void)in_sizes; (void)n_in; (void)out_size; (void)d_ws; (void)ws_size;
    const float* x    = (const float*)d_in[0];
    const float* Wih0 = (const float*)d_in[1];
    const float* Whh0 = (const float*)d_in[2];
    const float* bih0 = (const float*)d_in[3];
    const float* bhh0 = (const float*)d_in[4];
    const float* Wih1 = (const float*)d_in[5];
    const float* Whh1 = (const float*)d_in[6];
    const float* bih1 = (const float*)d_in[7];
    const float* bhh1 = (const float*)d_in[8];
    const float* gam  = (const float*)d_in[9];
    const float* bet  = (const float*)d_in[10];
    const float* Wfc  = (const float*)d_in[11];
    const float* bfc  = (const float*)d_in[12];
    float* out = (float*)d_out;

    hipLaunchKernelGGL(lstm2_ln_fc, dim3(NBLK), dim3(NW*64), 0, stream,
                       x, Wih0, Whh0, bih0, bhh0, Wih1, Whh1, bih1, bhh1,
                       gam, bet, Wfc, bfc, out);
}

// Round 3
// 2325.557 us; speedup vs baseline: 3.9885x; 3.1579x over previous
//
#include <hip/hip_runtime.h>

#define TSTEPS 100
#define DIN    4
#define HDIM   64
#define BC     64          // batch elements per block (lane = batch)
#define NW     16          // waves per block
#define UPW    4           // hidden units per wave
#define NBLK   (16384/BC)  // 256 blocks

// d_ws float layout:
//   [0      , 16384) Whh0'  [k][col]  col = wave*16 + u*4 + g
//   [16384  , 32768) Wih1'  [k][col]
//   [32768  , 49152) Whh1'  [k][col]
//   [49152  , 50176) Wih0'  [k<4][col]
//   [50176  , 50432) b0'    [col]  (bih0+bhh0 reordered)
//   [50432  , 50688) b1'    [col]
#define WS_WHH0 0
#define WS_WIH1 16384
#define WS_WHH1 32768
#define WS_WIH0 49152
#define WS_B0   50176
#define WS_B1   50432

__device__ __forceinline__ float fsig(float x) {
    return 1.0f / (1.0f + __expf(-x));
}
__device__ __forceinline__ float ftanh(float x) {
    float e = __expf(2.0f * x);
    return 1.0f - 2.0f / (e + 1.0f);
}

// One-shot weight reorder: grid 64 (k), block 256 (col).
__global__ void reorder_w(
    const float* __restrict__ Wih0, const float* __restrict__ Whh0,
    const float* __restrict__ bih0, const float* __restrict__ bhh0,
    const float* __restrict__ Wih1, const float* __restrict__ Whh1,
    const float* __restrict__ bih1, const float* __restrict__ bhh1,
    float* __restrict__ ws)
{
    const int k   = blockIdx.x;      // 0..63
    const int col = threadIdx.x;     // 0..255
    const int g = col & 3, u = (col >> 2) & 3, w = col >> 4;
    const int row = g * 64 + w * UPW + u;   // gate-major row in original [4H, *]
    ws[WS_WHH0 + k * 256 + col] = Whh0[row * HDIM + k];
    ws[WS_WIH1 + k * 256 + col] = Wih1[row * HDIM + k];
    ws[WS_WHH1 + k * 256 + col] = Whh1[row * HDIM + k];
    if (k < DIN) ws[WS_WIH0 + k * 256 + col] = Wih0[row * DIN + k];
    if (k == 0) {
        ws[WS_B0 + col] = bih0[row] + bhh0[row];
        ws[WS_B1 + col] = bih1[row] + bhh1[row];
    }
}

__global__ __launch_bounds__(NW*64, 1) void lstm2_ln_fc(
    const float* __restrict__ x,
    const float* __restrict__ ws,
    const float* __restrict__ gam,  const float* __restrict__ bet,
    const float* __restrict__ Wfc,  const float* __restrict__ bfc,
    float* __restrict__ out)
{
    // [unit][batch]: stride-1 across lanes -> conflict-free LDS
    __shared__ float H0[2][HDIM][BC];
    __shared__ float H1[2][HDIM][BC];

    const int lane = threadIdx.x & 63;
    const int wave = threadIdx.x >> 6;
    // Provably wave-uniform -> all weight accesses become s_load
    const int wv = __builtin_amdgcn_readfirstlane(wave);
    const int b  = blockIdx.x * BC + lane;

    const float* __restrict__ Whh0p = ws + WS_WHH0;
    const float* __restrict__ Wih1p = ws + WS_WIH1;
    const float* __restrict__ Whh1p = ws + WS_WHH1;
    const float* __restrict__ Wih0p = ws + WS_WIH0;

    // zero the t=0 read buffers
    #pragma unroll
    for (int u = 0; u < UPW; ++u) {
        H0[0][wv * UPW + u][lane] = 0.0f;
        H1[0][wv * UPW + u][lane] = 0.0f;
    }
    __syncthreads();

    // biases (wave-uniform, live in SGPRs/VGPRs across the whole t-loop)
    float bi0[16], bi1[16];
    #pragma unroll
    for (int i = 0; i < 16; ++i) {
        bi0[i] = ws[WS_B0 + wv * 16 + i];
        bi1[i] = ws[WS_B1 + wv * 16 + i];
    }

    float c0[UPW], c1[UPW];
    #pragma unroll
    for (int u = 0; u < UPW; ++u) { c0[u] = 0.0f; c1[u] = 0.0f; }

    const float4* __restrict__ xb =
        reinterpret_cast<const float4*>(x + (size_t)b * (TSTEPS * DIN));

    for (int t = 0; t < TSTEPS; ++t) {
        const int cur = t & 1, nxt = cur ^ 1;
        const float4 xv = xb[t];
        const float xa[4] = {xv.x, xv.y, xv.z, xv.w};

        // ---------------- layer 0 ----------------
        float acc[16];
        #pragma unroll
        for (int i = 0; i < 16; ++i) acc[i] = bi0[i];

        #pragma unroll
        for (int k = 0; k < DIN; ++k) {
            const float* wp = Wih0p + k * 256 + wv * 16;   // uniform -> s_load_x16
            const float xk = xa[k];
            #pragma unroll
            for (int i = 0; i < 16; ++i) acc[i] = fmaf(wp[i], xk, acc[i]);
        }

        #pragma unroll 8
        for (int k = 0; k < HDIM; ++k) {
            const float h = H0[cur][k][lane];              // 1 ds_read_b32
            const float* wp = Whh0p + k * 256 + wv * 16;   // 1 s_load_x16
            #pragma unroll
            for (int i = 0; i < 16; ++i) acc[i] = fmaf(wp[i], h, acc[i]);
        }

        #pragma unroll
        for (int u = 0; u < UPW; ++u) {
            const float ig = fsig(acc[u * 4 + 0]);
            const float fg = fsig(acc[u * 4 + 1]);
            const float gg = ftanh(acc[u * 4 + 2]);
            const float og = fsig(acc[u * 4 + 3]);
            const float c  = fg * c0[u] + ig * gg;
            c0[u] = c;
            H0[nxt][wv * UPW + u][lane] = og * ftanh(c);
        }
        __syncthreads();   // new h0 visible to all waves

        // ---------------- layer 1 ----------------
        #pragma unroll
        for (int i = 0; i < 16; ++i) acc[i] = bi1[i];

        #pragma unroll 8
        for (int k = 0; k < HDIM; ++k) {
            const float h0 = H0[nxt][k][lane];
            const float h1 = H1[cur][k][lane];
            const float* vp = Wih1p + k * 256 + wv * 16;
            const float* wp = Whh1p + k * 256 + wv * 16;
            #pragma unroll
            for (int i = 0; i < 16; ++i) acc[i] = fmaf(vp[i], h0, acc[i]);
            #pragma unroll
            for (int i = 0; i < 16; ++i) acc[i] = fmaf(wp[i], h1, acc[i]);
        }

        #pragma unroll
        for (int u = 0; u < UPW; ++u) {
            const float ig = fsig(acc[u * 4 + 0]);
            const float fg = fsig(acc[u * 4 + 1]);
            const float gg = ftanh(acc[u * 4 + 2]);
            const float og = fsig(acc[u * 4 + 3]);
            const float c  = fg * c1[u] + ig * gg;
            c1[u] = c;
            H1[nxt][wv * UPW + u][lane] = og * ftanh(c);
        }
        __syncthreads();
    }

    // ---------------- LayerNorm + FC on last h1 ----------------
    if (wave == 0) {
        const int fin = TSTEPS & 1;   // buffer holding h1[T-1]
        float hr[HDIM];
        float mu = 0.0f;
        #pragma unroll
        for (int k = 0; k < HDIM; ++k) { hr[k] = H1[fin][k][lane]; mu += hr[k]; }
        mu *= (1.0f / HDIM);
        float var = 0.0f;
        #pragma unroll
        for (int k = 0; k < HDIM; ++k) { const float d = hr[k] - mu; var = fmaf(d, d, var); }
        var *= (1.0f / HDIM);
        const float rs = rsqrtf(var + 1e-5f);
        float o0 = bfc[0], o1 = bfc[1];
        #pragma unroll
        for (int k = 0; k < HDIM; ++k) {
            const float nk = (hr[k] - mu) * rs * gam[k] + bet[k];
            o0 = fmaf(nk, Wfc[k],        o0);
            o1 = fmaf(nk, Wfc[HDIM + k], o1);
        }
        out[(size_t)b * 2 + 0] = o0;
        out[(size_t)b * 2 + 1] = o1;
    }
}

extern "C" void kernel_launch(void* const* d_in, const int* in_sizes, int n_in,
                              void* d_out, int out_size, void* d_ws, size_t ws_size,
                              hipStream_t stream) {
    (void)in_sizes; (void)n_in; (void)out_size; (void)ws_size;
    const float* x    = (const float*)d_in[0];
    const float* Wih0 = (const float*)d_in[1];
    const float* Whh0 = (const float*)d_in[2];
    const float* bih0 = (const float*)d_in[3];
    const float* bhh0 = (const float*)d_in[4];
    const float* Wih1 = (const float*)d_in[5];
    const float* Whh1 = (const float*)d_in[6];
    const float* bih1 = (const float*)d_in[7];
    const float* bhh1 = (const float*)d_in[8];
    const float* gam  = (const float*)d_in[9];
    const float* bet  = (const float*)d_in[10];
    const float* Wfc  = (const float*)d_in[11];
    const float* bfc  = (const float*)d_in[12];
    float* ws  = (float*)d_ws;
    float* out = (float*)d_out;

    hipLaunchKernelGGL(reorder_w, dim3(HDIM), dim3(256), 0, stream,
                       Wih0, Whh0, bih0, bhh0, Wih1, Whh1, bih1, bhh1, ws);
    hipLaunchKernelGGL(lstm2_ln_fc, dim3(NBLK), dim3(NW*64), 0, stream,
                       x, ws, gam, bet, Wfc, bfc, out);
}

// Round 4
// 604.330 us; speedup vs baseline: 15.3484x; 3.8482x over previous
//
#include <hip/hip_runtime.h>

#define TSTEPS 100
#define BC     32
#define NBLK   (16384/BC)   // 512 blocks

typedef __attribute__((ext_vector_type(8))) short bf16x8;
typedef __attribute__((ext_vector_type(4))) float f32x4;

// d_ws layout: ushort view for bf16 frags, float view for biases
#define WS_WHH0_U 0         // 16384 ushort
#define WS_WIH1_U 16384
#define WS_WHH1_U 32768
#define WS_WIH0_U 49152     // 8192 ushort -> ends at byte 114688
#define WS_B0_F   28672     // float idx (byte 114688)
#define WS_B1_F   28928

#define MFMA(A,B,C) __builtin_amdgcn_mfma_f32_16x16x32_bf16(A,B,C,0,0,0)

__device__ __forceinline__ unsigned short f2bf(float f) {
    unsigned int u = __float_as_uint(f);
    u += 0x7fffu + ((u >> 16) & 1u);
    return (unsigned short)(u >> 16);
}
__device__ __forceinline__ float fsig(float x) { return 1.0f / (1.0f + __expf(-x)); }
__device__ __forceinline__ float ftanh(float x) { float e = __expf(2.0f * x); return 1.0f - 2.0f / (e + 1.0f); }

// One-shot: format weights into per-lane MFMA B-fragment order (bf16) + fused biases.
// Frag (ug,G,kc): lane l, elem j  <->  W[row = G*64 + ug*16 + (l&15)][k = kc*32 + (l>>4)*8 + j]
__global__ void reorder_w(const float* __restrict__ Wih0, const float* __restrict__ Whh0,
                          const float* __restrict__ bih0, const float* __restrict__ bhh0,
                          const float* __restrict__ Wih1, const float* __restrict__ Whh1,
                          const float* __restrict__ bih1, const float* __restrict__ bhh1,
                          unsigned short* __restrict__ wsu, float* __restrict__ wsf)
{
    const int idx = blockIdx.x * 256 + threadIdx.x;   // 0..24575
    if (idx < 16384) {
        const int j = idx & 7, lane = (idx >> 3) & 63, kc = (idx >> 9) & 1,
                  G = (idx >> 10) & 3, ug = (idx >> 12) & 3;
        const int row = G * 64 + ug * 16 + (lane & 15);
        const int k   = kc * 32 + (lane >> 4) * 8 + j;
        wsu[WS_WHH0_U + idx] = f2bf(Whh0[row * 64 + k]);
        wsu[WS_WIH1_U + idx] = f2bf(Wih1[row * 64 + k]);
        wsu[WS_WHH1_U + idx] = f2bf(Whh1[row * 64 + k]);
    }
    if (idx < 8192) {
        const int j = idx & 7, lane = (idx >> 3) & 63, G = (idx >> 9) & 3, ug = (idx >> 11) & 3;
        const int row = G * 64 + ug * 16 + (lane & 15);
        const float v = ((lane >> 4) == 0 && j < 4) ? Wih0[row * 4 + j] : 0.0f;
        wsu[WS_WIH0_U + idx] = f2bf(v);
    }
    if (idx < 256) {
        wsf[WS_B0_F + idx] = bih0[idx] + bhh0[idx];
        wsf[WS_B1_F + idx] = bih1[idx] + bhh1[idx];
    }
}

__global__ __launch_bounds__(512, 2) void lstm2_mfma(
    const float* __restrict__ x,
    const unsigned short* __restrict__ wsu, const float* __restrict__ wsf,
    const float* __restrict__ gam, const float* __restrict__ bet,
    const float* __restrict__ Wfc, const float* __restrict__ bfc,
    float* __restrict__ out)
{
    // h as bf16 [batch][unit], pitch 72 (144B rows keep b128 frag reads 16B-aligned, ~2-way banks)
    __shared__ __align__(16) unsigned short H0[BC * 72];
    __shared__ __align__(16) unsigned short H1[BC * 72];
    __shared__ float H1F[BC * 65];   // f32 h1 for the LayerNorm epilogue

    const int tid  = threadIdx.x;
    const int lane = tid & 63;
    const int wv   = __builtin_amdgcn_readfirstlane(tid >> 6); // 0..7
    const int mt = wv >> 2, ug = wv & 3;      // batch-tile, unit-group
    const int ln15 = lane & 15, lg = lane >> 4;
    const int bblk = blockIdx.x * BC;

    // ---- load resident weight B-fragments (one-time) ----
    bf16x8 Bhh0[4][2], Bih1[4][2], Bhh1[4][2], Bih0[4];
    #pragma unroll
    for (int G = 0; G < 4; ++G) {
        #pragma unroll
        for (int kc = 0; kc < 2; ++kc) {
            const int f = ((ug * 4 + G) * 2 + kc) * 512 + lane * 8;
            Bhh0[G][kc] = *(const bf16x8*)(wsu + WS_WHH0_U + f);
            Bih1[G][kc] = *(const bf16x8*)(wsu + WS_WIH1_U + f);
            Bhh1[G][kc] = *(const bf16x8*)(wsu + WS_WHH1_U + f);
        }
        Bih0[G] = *(const bf16x8*)(wsu + WS_WIH0_U + (ug * 4 + G) * 512 + lane * 8);
    }
    float bias0[4], bias1[4];
    #pragma unroll
    for (int G = 0; G < 4; ++G) {
        bias0[G] = wsf[WS_B0_F + G * 64 + ug * 16 + ln15];
        bias1[G] = wsf[WS_B1_F + G * 64 + ug * 16 + ln15];
    }

    float c0[4] = {0.f,0.f,0.f,0.f}, c1[4] = {0.f,0.f,0.f,0.f};
    const bf16x8 zfrag = {0,0,0,0,0,0,0,0};
    bf16x8 A0[2], A1[2];
    A0[0] = zfrag; A0[1] = zfrag; A1[0] = zfrag; A1[1] = zfrag;   // h(-1) = 0

    const float* xb = x + (size_t)(bblk + mt * 16 + ln15) * (TSTEPS * 4);
    float4 xf = *(const float4*)(xb);   // x_0

    for (int t = 0; t < TSTEPS; ++t) {
        // ---------- layer 0 ----------
        bf16x8 ax = zfrag;
        if (lg == 0) {
            ax[0] = (short)f2bf(xf.x); ax[1] = (short)f2bf(xf.y);
            ax[2] = (short)f2bf(xf.z); ax[3] = (short)f2bf(xf.w);
        }
        f32x4 acc[4];
        #pragma unroll
        for (int G = 0; G < 4; ++G) {
            acc[G] = (f32x4){bias0[G], bias0[G], bias0[G], bias0[G]};
            acc[G] = MFMA(A0[0], Bhh0[G][0], acc[G]);
            acc[G] = MFMA(A0[1], Bhh0[G][1], acc[G]);
            acc[G] = MFMA(ax,    Bih0[G],    acc[G]);
        }
        if (t + 1 < TSTEPS) xf = *(const float4*)(xb + (t + 1) * 4);  // prefetch

        #pragma unroll
        for (int r = 0; r < 4; ++r) {
            const float ig = fsig(acc[0][r]), fg = fsig(acc[1][r]);
            const float gg = ftanh(acc[2][r]), og = fsig(acc[3][r]);
            const float c = fg * c0[r] + ig * gg; c0[r] = c;
            H0[(mt * 16 + lg * 4 + r) * 72 + ug * 16 + ln15] = f2bf(og * ftanh(c));
        }
        __syncthreads();
        A0[0] = *(const bf16x8*)(H0 + (mt * 16 + ln15) * 72 + lg * 8);
        A0[1] = *(const bf16x8*)(H0 + (mt * 16 + ln15) * 72 + 32 + lg * 8);

        // ---------- layer 1 ----------
        #pragma unroll
        for (int G = 0; G < 4; ++G) {
            acc[G] = (f32x4){bias1[G], bias1[G], bias1[G], bias1[G]};
            acc[G] = MFMA(A0[0], Bih1[G][0], acc[G]);
            acc[G] = MFMA(A0[1], Bih1[G][1], acc[G]);
            acc[G] = MFMA(A1[0], Bhh1[G][0], acc[G]);
            acc[G] = MFMA(A1[1], Bhh1[G][1], acc[G]);
        }
        #pragma unroll
        for (int r = 0; r < 4; ++r) {
            const float ig = fsig(acc[0][r]), fg = fsig(acc[1][r]);
            const float gg = ftanh(acc[2][r]), og = fsig(acc[3][r]);
            const float c = fg * c1[r] + ig * gg; c1[r] = c;
            const float h = og * ftanh(c);
            H1[(mt * 16 + lg * 4 + r) * 72 + ug * 16 + ln15] = f2bf(h);
            H1F[(mt * 16 + lg * 4 + r) * 65 + ug * 16 + ln15] = h;
        }
        __syncthreads();
        A1[0] = *(const bf16x8*)(H1 + (mt * 16 + ln15) * 72 + lg * 8);
        A1[1] = *(const bf16x8*)(H1 + (mt * 16 + ln15) * 72 + 32 + lg * 8);
    }

    // ---------- LayerNorm + FC on h1(T-1), f32 path ----------
    if (tid < BC) {
        const int b = tid;
        float hr[64];
        float mu = 0.f;
        #pragma unroll
        for (int k = 0; k < 64; ++k) { hr[k] = H1F[b * 65 + k]; mu += hr[k]; }
        mu *= (1.f / 64.f);
        float var = 0.f;
        #pragma unroll
        for (int k = 0; k < 64; ++k) { const float d = hr[k] - mu; var = fmaf(d, d, var); }
        var *= (1.f / 64.f);
        const float rs = rsqrtf(var + 1e-5f);
        float o0 = bfc[0], o1 = bfc[1];
        #pragma unroll
        for (int k = 0; k < 64; ++k) {
            const float nk = (hr[k] - mu) * rs * gam[k] + bet[k];
            o0 = fmaf(nk, Wfc[k],      o0);
            o1 = fmaf(nk, Wfc[64 + k], o1);
        }
        out[(size_t)(bblk + b) * 2 + 0] = o0;
        out[(size_t)(bblk + b) * 2 + 1] = o1;
    }
}

extern "C" void kernel_launch(void* const* d_in, const int* in_sizes, int n_in,
                              void* d_out, int out_size, void* d_ws, size_t ws_size,
                              hipStream_t stream) {
    (void)in_sizes; (void)n_in; (void)out_size; (void)ws_size;
    const float* x    = (const float*)d_in[0];
    const float* Wih0 = (const float*)d_in[1];
    const float* Whh0 = (const float*)d_in[2];
    const float* bih0 = (const float*)d_in[3];
    const float* bhh0 = (const float*)d_in[4];
    const float* Wih1 = (const float*)d_in[5];
    const float* Whh1 = (const float*)d_in[6];
    const float* bih1 = (const float*)d_in[7];
    const float* bhh1 = (const float*)d_in[8];
    const float* gam  = (const float*)d_in[9];
    const float* bet  = (const float*)d_in[10];
    const float* Wfc  = (const float*)d_in[11];
    const float* bfc  = (const float*)d_in[12];
    unsigned short* wsu = (unsigned short*)d_ws;
    float*          wsf = (float*)d_ws;
    float* out = (float*)d_out;

    hipLaunchKernelGGL(reorder_w, dim3(96), dim3(256), 0, stream,
                       Wih0, Whh0, bih0, bhh0, Wih1, Whh1, bih1, bhh1, wsu, wsf);
    hipLaunchKernelGGL(lstm2_mfma, dim3(NBLK), dim3(512), 0, stream,
                       x, wsu, wsf, gam, bet, Wfc, bfc, out);
}